// Round 6
// baseline (914.624 us; speedup 1.0000x reference)
//
#include <hip/hip_runtime.h>
#include <math.h>
#include <float.h>

#define NROWS 131072
#define SDIM 64
#define HDIM 128
#define KCODES 512
#define ADIM 8

// ===========================================================================
// prep: eT[j][c] = emb[c][j]  (256 KB) so per-j code-blocks are contiguous
// wave-uniform runs -> s_load_dwordx16 on the scalar pipe.
// ===========================================================================
__global__ void prep_e_kernel(const float* __restrict__ emb, float* __restrict__ eT) {
    int g = blockIdx.x * 256 + threadIdx.x;        // 0..16383
    int c = g >> 5, j4 = g & 31;
    float4 v = ((const float4*)emb)[(size_t)c * 32 + j4];
    eT[(size_t)(4 * j4 + 0) * KCODES + c] = v.x;
    eT[(size_t)(4 * j4 + 1) * KCODES + c] = v.y;
    eT[(size_t)(4 * j4 + 2) * KCODES + c] = v.z;
    eT[(size_t)(4 * j4 + 3) * KCODES + c] = v.w;
}

// ee[k] = sum_j emb[k][j]^2 — exact FP chain from rounds 1-5 (absmax 0.0)
__global__ void ee_kernel(const float* __restrict__ emb, float* __restrict__ ee) {
    int k = blockIdx.x * blockDim.x + threadIdx.x;
    if (k >= KCODES) return;
    const float* e = emb + k * HDIM;
    float a0 = 0.f, a1 = 0.f, a2 = 0.f, a3 = 0.f;
#pragma unroll
    for (int j = 0; j < HDIM; j += 4) {
        a0 = fmaf(e[j + 0], e[j + 0], a0);
        a1 = fmaf(e[j + 1], e[j + 1], a1);
        a2 = fmaf(e[j + 2], e[j + 2], a2);
        a3 = fmaf(e[j + 3], e[j + 3], a3);
    }
    ee[k] = (a0 + a1) + (a2 + a3);
}

// ===========================================================================
// MLP: block = 256 thr (4 waves) x 128 rows. lane l owns rows l, l+64;
// wave w owns cols w*32..w*32+31. Weights via wave-uniform s_load_dwordx16;
// x via conflict-free LDS. Chains: x1 s-ascending, x2 t-ascending (exact).
// x2 stored TRANSPOSED to ws: x2t[c][chunk_row] (coalesced b32 stores).
// ===========================================================================
__global__ __launch_bounds__(256, 2) void mlp_kernel(
    const float* __restrict__ in,
    const float* __restrict__ W1, const float* __restrict__ b1,
    const float* __restrict__ Wh, const float* __restrict__ bh,
    float* __restrict__ x2t, int row_base, int rstride)
{
    __shared__ float buf[16384];                  // 64 KB: inT(str 129) then x1T(str 128)
    const int tid = threadIdx.x;
    const int w = tid >> 6;                       // wave id (uniform per wave)
    const int l = tid & 63;
    const int brow = blockIdx.x * 128;            // row offset within chunk
    const int c0 = w * 32;

    // stage inT[s][r] = in[row][s], stride 129 (reads conflict-free: bank s+l)
    {
        const float4* src = (const float4*)(in + (size_t)(row_base + brow) * SDIM);
#pragma unroll
        for (int u = 0; u < 8; ++u) {
            int idx = tid + 256 * u;              // b128 units, 0..2047
            int r = idx >> 4, s4 = idx & 15;
            float4 v = src[idx];
            buf[(4 * s4 + 0) * 129 + r] = v.x;
            buf[(4 * s4 + 1) * 129 + r] = v.y;
            buf[(4 * s4 + 2) * 129 + r] = v.z;
            buf[(4 * s4 + 3) * 129 + r] = v.w;
        }
    }
    __syncthreads();

    float acc0[32], acc1[32];
#pragma unroll
    for (int cc = 0; cc < 32; ++cc) { acc0[cc] = b1[c0 + cc]; acc1[cc] = b1[c0 + cc]; }
#pragma unroll 8
    for (int s = 0; s < SDIM; ++s) {              // s ascending: exact chain
        float xa = buf[s * 129 + l];
        float xb = buf[s * 129 + l + 64];
        const float* wr = W1 + s * HDIM + c0;     // wave-uniform -> s_load x16
#pragma unroll
        for (int cc = 0; cc < 32; ++cc) {
            acc0[cc] = fmaf(xa, wr[cc], acc0[cc]);
            acc1[cc] = fmaf(xb, wr[cc], acc1[cc]);
        }
    }
    __syncthreads();                              // all inT reads done
    // x1T[c][r], stride 128 (write 2-way broadcast-free; read bank = l)
#pragma unroll
    for (int cc = 0; cc < 32; ++cc) {
        buf[(c0 + cc) * 128 + l]      = fmaxf(acc0[cc], 0.f);
        buf[(c0 + cc) * 128 + l + 64] = fmaxf(acc1[cc], 0.f);
    }
    __syncthreads();

#pragma unroll
    for (int cc = 0; cc < 32; ++cc) { acc0[cc] = bh[c0 + cc]; acc1[cc] = bh[c0 + cc]; }
#pragma unroll 8
    for (int t = 0; t < HDIM; ++t) {              // t ascending: exact chain
        float xa = buf[t * 128 + l];
        float xb = buf[t * 128 + l + 64];
        const float* wr = Wh + t * HDIM + c0;     // wave-uniform -> s_load x16
#pragma unroll
        for (int cc = 0; cc < 32; ++cc) {
            acc0[cc] = fmaf(xa, wr[cc], acc0[cc]);
            acc1[cc] = fmaf(xb, wr[cc], acc1[cc]);
        }
    }
    // store x2T (coalesced: lanes -> consecutive rows)
#pragma unroll
    for (int cc = 0; cc < 32; ++cc) {
        x2t[(size_t)(c0 + cc) * rstride + brow + l]      = fmaxf(acc0[cc], 0.f);
        x2t[(size_t)(c0 + cc) * rstride + brow + l + 64] = fmaxf(acc1[cc], 0.f);
    }
}

// ===========================================================================
// Score: block = 256 thr x 128 rows. lane l owns rows l, l+64; wave w owns
// codes w*128..w*128+127 in 4 groups of 32. x from LDS (j-half staged), e
// from eT via wave-uniform s_load_dwordx16, ee via uniform s_load.
// d-chain: j 0..127 ascending per (row,code) — exact. argmin: codes ascend
// within thread; cross-wave scan w ascending, strict < (first-min).
// ===========================================================================
__global__ __launch_bounds__(256, 4) void score_kernel(
    const float* __restrict__ x2t, const float* __restrict__ eT,
    const float* __restrict__ eew, const float* __restrict__ emb,
    const float* __restrict__ Wa, const float* __restrict__ ba,
    const float* __restrict__ Wv, const float* __restrict__ bv,
    float* __restrict__ out, int row_base, int rstride)
{
    __shared__ float xs[64 * 132];                // 33.8 KB, stride 132
    __shared__ float redb[4][128];
    __shared__ int   redi[4][128];
    const int tid = threadIdx.x;
    const int w = tid >> 6;                       // wave id (uniform)
    const int l = tid & 63;
    const int brow = blockIdx.x * 128;

#define STAGE(h) { __syncthreads(); \
    _Pragma("unroll") \
    for (int u = 0; u < 8; ++u) { \
        int idx = tid + 256 * u; int jl = idx >> 5; int rb = idx & 31; \
        float4 v = *(const float4*)(x2t + (size_t)((h) * 64 + jl) * rstride + brow + 4 * rb); \
        *(float4*)(xs + jl * 132 + 4 * rb) = v; } \
    __syncthreads(); }

    // --- vv pass: 4 chains by j%4, j ascending (exact round-1..5 order) ---
    float va0 = 0.f, va1 = 0.f, va2 = 0.f, va3 = 0.f;   // row l
    float vb0 = 0.f, vb1 = 0.f, vb2 = 0.f, vb3 = 0.f;   // row l+64
    STAGE(0)
#pragma unroll 4
    for (int j4 = 0; j4 < 16; ++j4) {
        int j = 4 * j4;
        float a0 = xs[(j + 0) * 132 + l], a1 = xs[(j + 1) * 132 + l];
        float a2 = xs[(j + 2) * 132 + l], a3 = xs[(j + 3) * 132 + l];
        float b0 = xs[(j + 0) * 132 + l + 64], b1_ = xs[(j + 1) * 132 + l + 64];
        float b2 = xs[(j + 2) * 132 + l + 64], b3 = xs[(j + 3) * 132 + l + 64];
        va0 = fmaf(a0, a0, va0); va1 = fmaf(a1, a1, va1);
        va2 = fmaf(a2, a2, va2); va3 = fmaf(a3, a3, va3);
        vb0 = fmaf(b0, b0, vb0); vb1 = fmaf(b1_, b1_, vb1);
        vb2 = fmaf(b2, b2, vb2); vb3 = fmaf(b3, b3, vb3);
    }
    STAGE(1)
#pragma unroll 4
    for (int j4 = 0; j4 < 16; ++j4) {
        int j = 4 * j4;
        float a0 = xs[(j + 0) * 132 + l], a1 = xs[(j + 1) * 132 + l];
        float a2 = xs[(j + 2) * 132 + l], a3 = xs[(j + 3) * 132 + l];
        float b0 = xs[(j + 0) * 132 + l + 64], b1_ = xs[(j + 1) * 132 + l + 64];
        float b2 = xs[(j + 2) * 132 + l + 64], b3 = xs[(j + 3) * 132 + l + 64];
        va0 = fmaf(a0, a0, va0); va1 = fmaf(a1, a1, va1);
        va2 = fmaf(a2, a2, va2); va3 = fmaf(a3, a3, va3);
        vb0 = fmaf(b0, b0, vb0); vb1 = fmaf(b1_, b1_, vb1);
        vb2 = fmaf(b2, b2, vb2); vb3 = fmaf(b3, b3, vb3);
    }
    const float vvA = (va0 + va1) + (va2 + va3);
    const float vvB = (vb0 + vb1) + (vb2 + vb3);

    // --- scoring: 4 groups of 32 codes per wave ---
    float bestA = FLT_MAX, bestB = FLT_MAX;
    int biA = 0, biB = 0;
    for (int g = 0; g < 4; ++g) {
        const int c0 = w * 128 + g * 32;
        float d0[32], d1[32];
#pragma unroll
        for (int cc = 0; cc < 32; ++cc) { d0[cc] = 0.f; d1[cc] = 0.f; }
        STAGE(0)
#pragma unroll 4
        for (int j = 0; j < 64; ++j) {
            float xa = xs[j * 132 + l];
            float xb = xs[j * 132 + l + 64];
            const float* er = eT + (size_t)j * KCODES + c0;   // uniform -> s_load x16
#pragma unroll
            for (int cc = 0; cc < 32; ++cc) {
                d0[cc] = fmaf(xa, er[cc], d0[cc]);
                d1[cc] = fmaf(xb, er[cc], d1[cc]);
            }
        }
        STAGE(1)
#pragma unroll 4
        for (int j = 0; j < 64; ++j) {
            float xa = xs[j * 132 + l];
            float xb = xs[j * 132 + l + 64];
            const float* er = eT + (size_t)(64 + j) * KCODES + c0;
#pragma unroll
            for (int cc = 0; cc < 32; ++cc) {
                d0[cc] = fmaf(xa, er[cc], d0[cc]);
                d1[cc] = fmaf(xb, er[cc], d1[cc]);
            }
        }
#pragma unroll
        for (int cc = 0; cc < 32; ++cc) {
            float ddA = (vvA - 2.f * d0[cc]) + eew[c0 + cc];
            if (ddA < bestA) { bestA = ddA; biA = c0 + cc; }
            float ddB = (vvB - 2.f * d1[cc]) + eew[c0 + cc];
            if (ddB < bestB) { bestB = ddB; biB = c0 + cc; }
        }
    }

    // --- cross-wave argmin reduction (w ascending = code-block ascending) ---
    redb[w][l] = bestA;       redi[w][l] = biA;
    redb[w][l + 64] = bestB;  redi[w][l + 64] = biB;
    __syncthreads();

    if (tid < 128) {
        float best = redb[0][tid];
        int bi = redi[0][tid];
#pragma unroll
        for (int q = 1; q < 4; ++q) {
            float b = redb[q][tid];
            if (b < best) { best = b; bi = redi[q][tid]; }
        }

        // --- heads: quantize = emb[bi]; exact FP order of rounds 1-5 ---
        const int row = row_base + brow + tid;
        float lg[ADIM];
#pragma unroll
        for (int a = 0; a < ADIM; ++a) lg[a] = ba[a];
        float val = bv[0];

        const float4* q4 = (const float4*)(emb + (size_t)bi * HDIM);
#pragma unroll
        for (int j4 = 0; j4 < HDIM / 4; ++j4) {
            float4 q = q4[j4];
            const int j = 4 * j4;
#pragma unroll
            for (int a = 0; a < ADIM; ++a) {
                float t = lg[a];
                t = fmaf(q.x, Wa[(j + 0) * ADIM + a], t);
                t = fmaf(q.y, Wa[(j + 1) * ADIM + a], t);
                t = fmaf(q.z, Wa[(j + 2) * ADIM + a], t);
                t = fmaf(q.w, Wa[(j + 3) * ADIM + a], t);
                lg[a] = t;
            }
            val = fmaf(q.x, Wv[j + 0], val);
            val = fmaf(q.y, Wv[j + 1], val);
            val = fmaf(q.z, Wv[j + 2], val);
            val = fmaf(q.w, Wv[j + 3], val);
        }

        float m = lg[0];
#pragma unroll
        for (int a = 1; a < ADIM; ++a) m = fmaxf(m, lg[a]);
        float p[ADIM];
        float s = 0.f;
#pragma unroll
        for (int a = 0; a < ADIM; ++a) { p[a] = __expf(lg[a] - m); s += p[a]; }
        const float inv = 1.f / s;

        float4* outp = (float4*)(out + (size_t)row * ADIM);
        outp[0] = make_float4(p[0] * inv, p[1] * inv, p[2] * inv, p[3] * inv);
        outp[1] = make_float4(p[4] * inv, p[5] * inv, p[6] * inv, p[7] * inv);
        out[(size_t)NROWS * ADIM + row] = val;
    }
#undef STAGE
}

// ===========================================================================
// Fallback (only if ws < 33.9 MB; never expected): round-4 global-feed path.
// ===========================================================================
#define R16(M) M(0) M(1) M(2) M(3) M(4) M(5) M(6) M(7) \
               M(8) M(9) M(10) M(11) M(12) M(13) M(14) M(15)
#define R32(M) R16(M) M(16) M(17) M(18) M(19) M(20) M(21) M(22) M(23) \
               M(24) M(25) M(26) M(27) M(28) M(29) M(30) M(31)
#define PIN4(v) asm volatile("" : "+v"(v.x), "+v"(v.y), "+v"(v.z), "+v"(v.w));

__global__ __launch_bounds__(256, 2) void fused_global_kernel(
    const float* __restrict__ in,
    const float* __restrict__ W1, const float* __restrict__ b1,
    const float* __restrict__ Wh, const float* __restrict__ bh,
    const float* __restrict__ emb,
    const float* __restrict__ Wa, const float* __restrict__ ba,
    const float* __restrict__ Wv, const float* __restrict__ bv,
    float* __restrict__ out)
{
    __shared__ float ee_s[KCODES];
    const int tid = threadIdx.x;
    const int row = blockIdx.x * 256 + tid;

#pragma unroll
    for (int kk = 0; kk < 2; ++kk) {
        int k = tid + 256 * kk;
        const float* e = emb + k * HDIM;
        float a0 = 0.f, a1 = 0.f, a2 = 0.f, a3 = 0.f;
#pragma unroll
        for (int j = 0; j < HDIM; j += 4) {
            a0 = fmaf(e[j + 0], e[j + 0], a0);
            a1 = fmaf(e[j + 1], e[j + 1], a1);
            a2 = fmaf(e[j + 2], e[j + 2], a2);
            a3 = fmaf(e[j + 3], e[j + 3], a3);
        }
        ee_s[k] = (a0 + a1) + (a2 + a3);
    }
    __syncthreads();

    const float4* inr4 = (const float4*)(in + (size_t)row * SDIM);
#define DECLI(n) float4 i##n = inr4[n]; PIN4(i##n)
    R16(DECLI)
#define DECLX(m) float4 x##m = make_float4(bh[4*(m)+0], bh[4*(m)+1], bh[4*(m)+2], bh[4*(m)+3]);
    R32(DECLX)

#define L1N(n) xt = fmaf(i##n.x, wc[(4*(n)+0)*HDIM], xt); xt = fmaf(i##n.y, wc[(4*(n)+1)*HDIM], xt); \
               xt = fmaf(i##n.z, wc[(4*(n)+2)*HDIM], xt); xt = fmaf(i##n.w, wc[(4*(n)+3)*HDIM], xt);
#define L2(m)  x##m.x = fmaf(xt, whr[4*(m)+0], x##m.x); x##m.y = fmaf(xt, whr[4*(m)+1], x##m.y); \
               x##m.z = fmaf(xt, whr[4*(m)+2], x##m.z); x##m.w = fmaf(xt, whr[4*(m)+3], x##m.w);
    for (int t = 0; t < HDIM; ++t) {
        float xt = b1[t];
        const float* wc = W1 + t;
        R16(L1N)
        xt = fmaxf(xt, 0.f);
        const float* whr = Wh + t * HDIM;
        R32(L2)
    }
#define RELUX(m) x##m.x = fmaxf(x##m.x, 0.f); x##m.y = fmaxf(x##m.y, 0.f); \
                 x##m.z = fmaxf(x##m.z, 0.f); x##m.w = fmaxf(x##m.w, 0.f); PIN4(x##m)
    R32(RELUX)

    float v0 = 0.f, v1 = 0.f, v2 = 0.f, v3 = 0.f;
#define VV(m) v0 = fmaf(x##m.x, x##m.x, v0); v1 = fmaf(x##m.y, x##m.y, v1); \
              v2 = fmaf(x##m.z, x##m.z, v2); v3 = fmaf(x##m.w, x##m.w, v3);
    R32(VV)
    const float vv = (v0 + v1) + (v2 + v3);

    float best = FLT_MAX;
    int bi = 0;
#define SC(m) \
    d0 = fmaf(x##m.x, eb[0*HDIM+4*(m)+0], d0); d0 = fmaf(x##m.y, eb[0*HDIM+4*(m)+1], d0); \
    d0 = fmaf(x##m.z, eb[0*HDIM+4*(m)+2], d0); d0 = fmaf(x##m.w, eb[0*HDIM+4*(m)+3], d0); \
    d1 = fmaf(x##m.x, eb[1*HDIM+4*(m)+0], d1); d1 = fmaf(x##m.y, eb[1*HDIM+4*(m)+1], d1); \
    d1 = fmaf(x##m.z, eb[1*HDIM+4*(m)+2], d1); d1 = fmaf(x##m.w, eb[1*HDIM+4*(m)+3], d1); \
    d2 = fmaf(x##m.x, eb[2*HDIM+4*(m)+0], d2); d2 = fmaf(x##m.y, eb[2*HDIM+4*(m)+1], d2); \
    d2 = fmaf(x##m.z, eb[2*HDIM+4*(m)+2], d2); d2 = fmaf(x##m.w, eb[2*HDIM+4*(m)+3], d2); \
    d3 = fmaf(x##m.x, eb[3*HDIM+4*(m)+0], d3); d3 = fmaf(x##m.y, eb[3*HDIM+4*(m)+1], d3); \
    d3 = fmaf(x##m.z, eb[3*HDIM+4*(m)+2], d3); d3 = fmaf(x##m.w, eb[3*HDIM+4*(m)+3], d3); \
    d4 = fmaf(x##m.x, eb[4*HDIM+4*(m)+0], d4); d4 = fmaf(x##m.y, eb[4*HDIM+4*(m)+1], d4); \
    d4 = fmaf(x##m.z, eb[4*HDIM+4*(m)+2], d4); d4 = fmaf(x##m.w, eb[4*HDIM+4*(m)+3], d4); \
    d5 = fmaf(x##m.x, eb[5*HDIM+4*(m)+0], d5); d5 = fmaf(x##m.y, eb[5*HDIM+4*(m)+1], d5); \
    d5 = fmaf(x##m.z, eb[5*HDIM+4*(m)+2], d5); d5 = fmaf(x##m.w, eb[5*HDIM+4*(m)+3], d5); \
    d6 = fmaf(x##m.x, eb[6*HDIM+4*(m)+0], d6); d6 = fmaf(x##m.y, eb[6*HDIM+4*(m)+1], d6); \
    d6 = fmaf(x##m.z, eb[6*HDIM+4*(m)+2], d6); d6 = fmaf(x##m.w, eb[6*HDIM+4*(m)+3], d6); \
    d7 = fmaf(x##m.x, eb[7*HDIM+4*(m)+0], d7); d7 = fmaf(x##m.y, eb[7*HDIM+4*(m)+1], d7); \
    d7 = fmaf(x##m.z, eb[7*HDIM+4*(m)+2], d7); d7 = fmaf(x##m.w, eb[7*HDIM+4*(m)+3], d7);
    for (int k0 = 0; k0 < KCODES; k0 += 8) {
        const float* eb = emb + (size_t)k0 * HDIM;
        float d0 = 0.f, d1 = 0.f, d2 = 0.f, d3 = 0.f;
        float d4 = 0.f, d5 = 0.f, d6 = 0.f, d7 = 0.f;
        R32(SC)
        float dd;
        dd = (vv - 2.f * d0) + ee_s[k0 + 0]; if (dd < best) { best = dd; bi = k0 + 0; }
        dd = (vv - 2.f * d1) + ee_s[k0 + 1]; if (dd < best) { best = dd; bi = k0 + 1; }
        dd = (vv - 2.f * d2) + ee_s[k0 + 2]; if (dd < best) { best = dd; bi = k0 + 2; }
        dd = (vv - 2.f * d3) + ee_s[k0 + 3]; if (dd < best) { best = dd; bi = k0 + 3; }
        dd = (vv - 2.f * d4) + ee_s[k0 + 4]; if (dd < best) { best = dd; bi = k0 + 4; }
        dd = (vv - 2.f * d5) + ee_s[k0 + 5]; if (dd < best) { best = dd; bi = k0 + 5; }
        dd = (vv - 2.f * d6) + ee_s[k0 + 6]; if (dd < best) { best = dd; bi = k0 + 6; }
        dd = (vv - 2.f * d7) + ee_s[k0 + 7]; if (dd < best) { best = dd; bi = k0 + 7; }
    }

    float lg[ADIM];
#pragma unroll
    for (int a = 0; a < ADIM; ++a) lg[a] = ba[a];
    float val = bv[0];
    const float4* q4 = (const float4*)(emb + (size_t)bi * HDIM);
#pragma unroll
    for (int j4 = 0; j4 < HDIM / 4; ++j4) {
        float4 q = q4[j4];
        const int j = 4 * j4;
#pragma unroll
        for (int a = 0; a < ADIM; ++a) {
            float t = lg[a];
            t = fmaf(q.x, Wa[(j + 0) * ADIM + a], t);
            t = fmaf(q.y, Wa[(j + 1) * ADIM + a], t);
            t = fmaf(q.z, Wa[(j + 2) * ADIM + a], t);
            t = fmaf(q.w, Wa[(j + 3) * ADIM + a], t);
            lg[a] = t;
        }
        val = fmaf(q.x, Wv[j + 0], val);
        val = fmaf(q.y, Wv[j + 1], val);
        val = fmaf(q.z, Wv[j + 2], val);
        val = fmaf(q.w, Wv[j + 3], val);
    }
    float m = lg[0];
#pragma unroll
    for (int a = 1; a < ADIM; ++a) m = fmaxf(m, lg[a]);
    float p[ADIM];
    float s = 0.f;
#pragma unroll
    for (int a = 0; a < ADIM; ++a) { p[a] = __expf(lg[a] - m); s += p[a]; }
    const float inv = 1.f / s;
    float4* outp = (float4*)(out + (size_t)row * ADIM);
    outp[0] = make_float4(p[0] * inv, p[1] * inv, p[2] * inv, p[3] * inv);
    outp[1] = make_float4(p[4] * inv, p[5] * inv, p[6] * inv, p[7] * inv);
    out[(size_t)NROWS * ADIM + row] = val;
}

// ===========================================================================
extern "C" void kernel_launch(void* const* d_in, const int* in_sizes, int n_in,
                              void* d_out, int out_size, void* d_ws, size_t ws_size,
                              hipStream_t stream) {
    const float* in  = (const float*)d_in[0];
    const float* W1  = (const float*)d_in[1];
    const float* b1  = (const float*)d_in[2];
    const float* Wh  = (const float*)d_in[3];
    const float* bh  = (const float*)d_in[4];
    const float* emb = (const float*)d_in[5];
    const float* Wa  = (const float*)d_in[6];
    const float* ba  = (const float*)d_in[7];
    const float* Wv  = (const float*)d_in[8];
    const float* bv  = (const float*)d_in[9];
    float* out = (float*)d_out;

    const size_t eT_bytes = (size_t)KCODES * HDIM * sizeof(float);   // 256 KB
    const size_t ee_bytes = KCODES * sizeof(float);                  // 2 KB
    const size_t need1 = (size_t)NROWS * HDIM * sizeof(float) + eT_bytes + ee_bytes;
    const size_t need2 = (size_t)(NROWS / 2) * HDIM * sizeof(float) + eT_bytes + ee_bytes;

    int nchunks, rstride;
    if (ws_size >= need1)      { nchunks = 1; rstride = NROWS; }
    else if (ws_size >= need2) { nchunks = 2; rstride = NROWS / 2; }
    else {
        fused_global_kernel<<<NROWS / 256, 256, 0, stream>>>(in, W1, b1, Wh, bh, emb,
                                                             Wa, ba, Wv, bv, out);
        return;
    }

    float* x2t = (float*)d_ws;
    float* eTp = x2t + (size_t)rstride * HDIM;
    float* eew = eTp + (size_t)KCODES * HDIM;

    prep_e_kernel<<<64, 256, 0, stream>>>(emb, eTp);
    ee_kernel<<<2, 256, 0, stream>>>(emb, eew);

    for (int c = 0; c < nchunks; ++c) {
        mlp_kernel<<<rstride / 128, 256, 0, stream>>>(in, W1, b1, Wh, bh,
                                                      x2t, c * rstride, rstride);
        score_kernel<<<rstride / 128, 256, 0, stream>>>(x2t, eTp, eew, emb,
                                                        Wa, ba, Wv, bv, out,
                                                        c * rstride, rstride);
    }
}

// Round 7
// 432.863 us; speedup vs baseline: 2.1130x; 2.1130x over previous
//
#include <hip/hip_runtime.h>
#include <math.h>
#include <float.h>

#define NROWS 131072
#define SDIM 64
#define HDIM 128
#define KCODES 512
#define ADIM 8

// ===========================================================================
// prep: eT[j][c] = emb[c][j]  (256 KB) so per-j code-blocks are contiguous
// wave-uniform runs -> s_load_dwordx16 on the scalar pipe.
// ===========================================================================
__global__ void prep_e_kernel(const float* __restrict__ emb, float* __restrict__ eT) {
    int g = blockIdx.x * 256 + threadIdx.x;        // 0..16383
    int c = g >> 5, j4 = g & 31;
    float4 v = ((const float4*)emb)[(size_t)c * 32 + j4];
    eT[(size_t)(4 * j4 + 0) * KCODES + c] = v.x;
    eT[(size_t)(4 * j4 + 1) * KCODES + c] = v.y;
    eT[(size_t)(4 * j4 + 2) * KCODES + c] = v.z;
    eT[(size_t)(4 * j4 + 3) * KCODES + c] = v.w;
}

// ee[k] = sum_j emb[k][j]^2 — exact FP chain from rounds 1-6 (absmax 0.0)
__global__ void ee_kernel(const float* __restrict__ emb, float* __restrict__ ee) {
    int k = blockIdx.x * blockDim.x + threadIdx.x;
    if (k >= KCODES) return;
    const float* e = emb + k * HDIM;
    float a0 = 0.f, a1 = 0.f, a2 = 0.f, a3 = 0.f;
#pragma unroll
    for (int j = 0; j < HDIM; j += 4) {
        a0 = fmaf(e[j + 0], e[j + 0], a0);
        a1 = fmaf(e[j + 1], e[j + 1], a1);
        a2 = fmaf(e[j + 2], e[j + 2], a2);
        a3 = fmaf(e[j + 3], e[j + 3], a3);
    }
    ee[k] = (a0 + a1) + (a2 + a3);
}

// ===========================================================================
// MLP: block = 256 thr (4 waves) x 128 rows. lane l owns rows l, l+64;
// wave w owns cols [wu*32, wu*32+32) — wu via readfirstlane so weight reads
// are PROVABLY wave-uniform -> s_load_dwordx16 (values in SGPRs, zero VGPR
// cost). Chains: x1 s-ascending, x2 t-ascending (exact rounds 1-6 order).
// x2 stored TRANSPOSED to ws: x2t[c][chunk_row].
// ===========================================================================
__global__ __launch_bounds__(256, 2) void mlp_kernel(
    const float* __restrict__ in,
    const float* __restrict__ W1, const float* __restrict__ b1,
    const float* __restrict__ Wh, const float* __restrict__ bh,
    float* __restrict__ x2t, int row_base, int rstride)
{
    __shared__ float buf[16384];                  // 64 KB: inT(str 129) then x1T(str 128)
    const int tid = threadIdx.x;
    const int wu = __builtin_amdgcn_readfirstlane(tid >> 6);  // uniform wave id
    const int l = tid & 63;
    const int brow = blockIdx.x * 128;            // row offset within chunk
    const int c0 = wu * 32;                       // uniform col base

    // stage inT[s][r] = in[row][s], stride 129
    {
        const float4* src = (const float4*)(in + (size_t)(row_base + brow) * SDIM);
#pragma unroll
        for (int u = 0; u < 8; ++u) {
            int idx = tid + 256 * u;              // b128 units, 0..2047
            int r = idx >> 4, s4 = idx & 15;
            float4 v = src[idx];
            buf[(4 * s4 + 0) * 129 + r] = v.x;
            buf[(4 * s4 + 1) * 129 + r] = v.y;
            buf[(4 * s4 + 2) * 129 + r] = v.z;
            buf[(4 * s4 + 3) * 129 + r] = v.w;
        }
    }
    __syncthreads();

    float acc0[32], acc1[32];
#pragma unroll
    for (int cc = 0; cc < 32; ++cc) { acc0[cc] = b1[c0 + cc]; acc1[cc] = b1[c0 + cc]; }
#pragma unroll 4
    for (int s = 0; s < SDIM; ++s) {              // s ascending: exact chain
        float xa = buf[s * 129 + l];
        float xb = buf[s * 129 + l + 64];
        const float* wr = W1 + s * HDIM + c0;     // uniform -> s_load x16
#pragma unroll
        for (int cc = 0; cc < 32; ++cc) {
            acc0[cc] = fmaf(xa, wr[cc], acc0[cc]);
            acc1[cc] = fmaf(xb, wr[cc], acc1[cc]);
        }
    }
    __syncthreads();                              // all inT reads done
    // x1T[c][r], stride 128
#pragma unroll
    for (int cc = 0; cc < 32; ++cc) {
        buf[(c0 + cc) * 128 + l]      = fmaxf(acc0[cc], 0.f);
        buf[(c0 + cc) * 128 + l + 64] = fmaxf(acc1[cc], 0.f);
    }
    __syncthreads();

#pragma unroll
    for (int cc = 0; cc < 32; ++cc) { acc0[cc] = bh[c0 + cc]; acc1[cc] = bh[c0 + cc]; }
#pragma unroll 4
    for (int t = 0; t < HDIM; ++t) {              // t ascending: exact chain
        float xa = buf[t * 128 + l];
        float xb = buf[t * 128 + l + 64];
        const float* wr = Wh + t * HDIM + c0;     // uniform -> s_load x16
#pragma unroll
        for (int cc = 0; cc < 32; ++cc) {
            acc0[cc] = fmaf(xa, wr[cc], acc0[cc]);
            acc1[cc] = fmaf(xb, wr[cc], acc1[cc]);
        }
    }
    // store x2T (coalesced: lanes -> consecutive rows)
#pragma unroll
    for (int cc = 0; cc < 32; ++cc) {
        x2t[(size_t)(c0 + cc) * rstride + brow + l]      = fmaxf(acc0[cc], 0.f);
        x2t[(size_t)(c0 + cc) * rstride + brow + l + 64] = fmaxf(acc1[cc], 0.f);
    }
}

// ===========================================================================
// Score: block = 256 thr x 128 rows. Full 128x128 x-tile staged to LDS ONCE
// (67.6 KB, stride 132). lane l owns rows l, l+64; wave wu owns codes
// [wu*128, wu*128+128) in 4 groups of 32. eT/ee via uniform s_load (SGPRs).
// d-chain: j 0..127 ascending per (row,code) — exact. argmin: codes ascend
// within thread; cross-wave scan q ascending, strict < (first-min). Exact.
// ===========================================================================
__global__ __launch_bounds__(256, 2) void score_kernel(
    const float* __restrict__ x2t, const float* __restrict__ eT,
    const float* __restrict__ eew, const float* __restrict__ emb,
    const float* __restrict__ Wa, const float* __restrict__ ba,
    const float* __restrict__ Wv, const float* __restrict__ bv,
    float* __restrict__ out, int row_base, int rstride)
{
    __shared__ float xs[128 * 132];               // 67.6 KB
    __shared__ float redb[4][128];
    __shared__ int   redi[4][128];
    const int tid = threadIdx.x;
    const int wu = __builtin_amdgcn_readfirstlane(tid >> 6);  // uniform wave id
    const int l = tid & 63;
    const int brow = blockIdx.x * 128;

    // stage full x tile: xs[j][r] = x2t[j][brow+r]
#pragma unroll
    for (int u = 0; u < 16; ++u) {
        int idx = tid + 256 * u;                  // 0..4095 (b128 units)
        int jl = idx >> 5, rb = idx & 31;
        float4 v = *(const float4*)(x2t + (size_t)jl * rstride + brow + 4 * rb);
        *(float4*)(xs + jl * 132 + 4 * rb) = v;
    }
    __syncthreads();

    // --- vv: 4 chains by j%4, j ascending (exact round-1..6 order) ---
    float va0 = 0.f, va1 = 0.f, va2 = 0.f, va3 = 0.f;   // row l
    float vb0 = 0.f, vb1 = 0.f, vb2 = 0.f, vb3 = 0.f;   // row l+64
#pragma unroll 4
    for (int j4 = 0; j4 < 32; ++j4) {
        int j = 4 * j4;
        float a0 = xs[(j + 0) * 132 + l], a1 = xs[(j + 1) * 132 + l];
        float a2 = xs[(j + 2) * 132 + l], a3 = xs[(j + 3) * 132 + l];
        float b0 = xs[(j + 0) * 132 + l + 64], b1_ = xs[(j + 1) * 132 + l + 64];
        float b2 = xs[(j + 2) * 132 + l + 64], b3 = xs[(j + 3) * 132 + l + 64];
        va0 = fmaf(a0, a0, va0); va1 = fmaf(a1, a1, va1);
        va2 = fmaf(a2, a2, va2); va3 = fmaf(a3, a3, va3);
        vb0 = fmaf(b0, b0, vb0); vb1 = fmaf(b1_, b1_, vb1);
        vb2 = fmaf(b2, b2, vb2); vb3 = fmaf(b3, b3, vb3);
    }
    const float vvA = (va0 + va1) + (va2 + va3);
    const float vvB = (vb0 + vb1) + (vb2 + vb3);

    // --- scoring: 4 groups of 32 codes per wave, no re-staging ---
    float bestA = FLT_MAX, bestB = FLT_MAX;
    int biA = 0, biB = 0;
    for (int g = 0; g < 4; ++g) {
        const int c0 = wu * 128 + g * 32;                 // uniform
        float d0[32], d1[32];
#pragma unroll
        for (int cc = 0; cc < 32; ++cc) { d0[cc] = 0.f; d1[cc] = 0.f; }
#pragma unroll 2
        for (int j = 0; j < HDIM; ++j) {                  // j ascending: exact
            float xa = xs[j * 132 + l];
            float xb = xs[j * 132 + l + 64];
            const float* er = eT + (size_t)j * KCODES + c0;   // uniform -> s_load x16
#pragma unroll
            for (int cc = 0; cc < 32; ++cc) {
                d0[cc] = fmaf(xa, er[cc], d0[cc]);
                d1[cc] = fmaf(xb, er[cc], d1[cc]);
            }
        }
        const float* eg = eew + c0;                       // uniform -> s_load
#pragma unroll
        for (int cc = 0; cc < 32; ++cc) {
            float ddA = (vvA - 2.f * d0[cc]) + eg[cc];
            if (ddA < bestA) { bestA = ddA; biA = c0 + cc; }
            float ddB = (vvB - 2.f * d1[cc]) + eg[cc];
            if (ddB < bestB) { bestB = ddB; biB = c0 + cc; }
        }
    }

    // --- cross-wave argmin reduction (q ascending = code-block ascending) ---
    const int w = tid >> 6;
    redb[w][l] = bestA;       redi[w][l] = biA;
    redb[w][l + 64] = bestB;  redi[w][l + 64] = biB;
    __syncthreads();

    if (tid < 128) {
        float best = redb[0][tid];
        int bi = redi[0][tid];
#pragma unroll
        for (int q = 1; q < 4; ++q) {
            float b = redb[q][tid];
            if (b < best) { best = b; bi = redi[q][tid]; }
        }

        // --- heads: quantize = emb[bi]; exact FP order of rounds 1-6 ---
        const int row = row_base + brow + tid;
        float lg[ADIM];
#pragma unroll
        for (int a = 0; a < ADIM; ++a) lg[a] = ba[a];
        float val = bv[0];

        const float4* q4 = (const float4*)(emb + (size_t)bi * HDIM);
#pragma unroll
        for (int j4 = 0; j4 < HDIM / 4; ++j4) {
            float4 q = q4[j4];
            const int j = 4 * j4;
#pragma unroll
            for (int a = 0; a < ADIM; ++a) {
                float t = lg[a];
                t = fmaf(q.x, Wa[(j + 0) * ADIM + a], t);
                t = fmaf(q.y, Wa[(j + 1) * ADIM + a], t);
                t = fmaf(q.z, Wa[(j + 2) * ADIM + a], t);
                t = fmaf(q.w, Wa[(j + 3) * ADIM + a], t);
                lg[a] = t;
            }
            val = fmaf(q.x, Wv[j + 0], val);
            val = fmaf(q.y, Wv[j + 1], val);
            val = fmaf(q.z, Wv[j + 2], val);
            val = fmaf(q.w, Wv[j + 3], val);
        }

        float m = lg[0];
#pragma unroll
        for (int a = 1; a < ADIM; ++a) m = fmaxf(m, lg[a]);
        float p[ADIM];
        float s = 0.f;
#pragma unroll
        for (int a = 0; a < ADIM; ++a) { p[a] = __expf(lg[a] - m); s += p[a]; }
        const float inv = 1.f / s;

        float4* outp = (float4*)(out + (size_t)row * ADIM);
        outp[0] = make_float4(p[0] * inv, p[1] * inv, p[2] * inv, p[3] * inv);
        outp[1] = make_float4(p[4] * inv, p[5] * inv, p[6] * inv, p[7] * inv);
        out[(size_t)NROWS * ADIM + row] = val;
    }
}

// ===========================================================================
// Fallback (only if ws tiny; never expected): round-4 global-feed path.
// ===========================================================================
#define R16(M) M(0) M(1) M(2) M(3) M(4) M(5) M(6) M(7) \
               M(8) M(9) M(10) M(11) M(12) M(13) M(14) M(15)
#define R32(M) R16(M) M(16) M(17) M(18) M(19) M(20) M(21) M(22) M(23) \
               M(24) M(25) M(26) M(27) M(28) M(29) M(30) M(31)
#define PIN4(v) asm volatile("" : "+v"(v.x), "+v"(v.y), "+v"(v.z), "+v"(v.w));

__global__ __launch_bounds__(256, 2) void fused_global_kernel(
    const float* __restrict__ in,
    const float* __restrict__ W1, const float* __restrict__ b1,
    const float* __restrict__ Wh, const float* __restrict__ bh,
    const float* __restrict__ emb,
    const float* __restrict__ Wa, const float* __restrict__ ba,
    const float* __restrict__ Wv, const float* __restrict__ bv,
    float* __restrict__ out)
{
    __shared__ float ee_s[KCODES];
    const int tid = threadIdx.x;
    const int row = blockIdx.x * 256 + tid;

#pragma unroll
    for (int kk = 0; kk < 2; ++kk) {
        int k = tid + 256 * kk;
        const float* e = emb + k * HDIM;
        float a0 = 0.f, a1 = 0.f, a2 = 0.f, a3 = 0.f;
#pragma unroll
        for (int j = 0; j < HDIM; j += 4) {
            a0 = fmaf(e[j + 0], e[j + 0], a0);
            a1 = fmaf(e[j + 1], e[j + 1], a1);
            a2 = fmaf(e[j + 2], e[j + 2], a2);
            a3 = fmaf(e[j + 3], e[j + 3], a3);
        }
        ee_s[k] = (a0 + a1) + (a2 + a3);
    }
    __syncthreads();

    const float4* inr4 = (const float4*)(in + (size_t)row * SDIM);
#define DECLI(n) float4 i##n = inr4[n]; PIN4(i##n)
    R16(DECLI)
#define DECLX(m) float4 x##m = make_float4(bh[4*(m)+0], bh[4*(m)+1], bh[4*(m)+2], bh[4*(m)+3]);
    R32(DECLX)

#define L1N(n) xt = fmaf(i##n.x, wc[(4*(n)+0)*HDIM], xt); xt = fmaf(i##n.y, wc[(4*(n)+1)*HDIM], xt); \
               xt = fmaf(i##n.z, wc[(4*(n)+2)*HDIM], xt); xt = fmaf(i##n.w, wc[(4*(n)+3)*HDIM], xt);
#define L2(m)  x##m.x = fmaf(xt, whr[4*(m)+0], x##m.x); x##m.y = fmaf(xt, whr[4*(m)+1], x##m.y); \
               x##m.z = fmaf(xt, whr[4*(m)+2], x##m.z); x##m.w = fmaf(xt, whr[4*(m)+3], x##m.w);
    for (int t = 0; t < HDIM; ++t) {
        float xt = b1[t];
        const float* wc = W1 + t;
        R16(L1N)
        xt = fmaxf(xt, 0.f);
        const float* whr = Wh + t * HDIM;
        R32(L2)
    }
#define RELUX(m) x##m.x = fmaxf(x##m.x, 0.f); x##m.y = fmaxf(x##m.y, 0.f); \
                 x##m.z = fmaxf(x##m.z, 0.f); x##m.w = fmaxf(x##m.w, 0.f); PIN4(x##m)
    R32(RELUX)

    float v0 = 0.f, v1 = 0.f, v2 = 0.f, v3 = 0.f;
#define VV(m) v0 = fmaf(x##m.x, x##m.x, v0); v1 = fmaf(x##m.y, x##m.y, v1); \
              v2 = fmaf(x##m.z, x##m.z, v2); v3 = fmaf(x##m.w, x##m.w, v3);
    R32(VV)
    const float vv = (v0 + v1) + (v2 + v3);

    float best = FLT_MAX;
    int bi = 0;
#define SC(m) \
    d0 = fmaf(x##m.x, eb[0*HDIM+4*(m)+0], d0); d0 = fmaf(x##m.y, eb[0*HDIM+4*(m)+1], d0); \
    d0 = fmaf(x##m.z, eb[0*HDIM+4*(m)+2], d0); d0 = fmaf(x##m.w, eb[0*HDIM+4*(m)+3], d0); \
    d1 = fmaf(x##m.x, eb[1*HDIM+4*(m)+0], d1); d1 = fmaf(x##m.y, eb[1*HDIM+4*(m)+1], d1); \
    d1 = fmaf(x##m.z, eb[1*HDIM+4*(m)+2], d1); d1 = fmaf(x##m.w, eb[1*HDIM+4*(m)+3], d1); \
    d2 = fmaf(x##m.x, eb[2*HDIM+4*(m)+0], d2); d2 = fmaf(x##m.y, eb[2*HDIM+4*(m)+1], d2); \
    d2 = fmaf(x##m.z, eb[2*HDIM+4*(m)+2], d2); d2 = fmaf(x##m.w, eb[2*HDIM+4*(m)+3], d2); \
    d3 = fmaf(x##m.x, eb[3*HDIM+4*(m)+0], d3); d3 = fmaf(x##m.y, eb[3*HDIM+4*(m)+1], d3); \
    d3 = fmaf(x##m.z, eb[3*HDIM+4*(m)+2], d3); d3 = fmaf(x##m.w, eb[3*HDIM+4*(m)+3], d3); \
    d4 = fmaf(x##m.x, eb[4*HDIM+4*(m)+0], d4); d4 = fmaf(x##m.y, eb[4*HDIM+4*(m)+1], d4); \
    d4 = fmaf(x##m.z, eb[4*HDIM+4*(m)+2], d4); d4 = fmaf(x##m.w, eb[4*HDIM+4*(m)+3], d4); \
    d5 = fmaf(x##m.x, eb[5*HDIM+4*(m)+0], d5); d5 = fmaf(x##m.y, eb[5*HDIM+4*(m)+1], d5); \
    d5 = fmaf(x##m.z, eb[5*HDIM+4*(m)+2], d5); d5 = fmaf(x##m.w, eb[5*HDIM+4*(m)+3], d5); \
    d6 = fmaf(x##m.x, eb[6*HDIM+4*(m)+0], d6); d6 = fmaf(x##m.y, eb[6*HDIM+4*(m)+1], d6); \
    d6 = fmaf(x##m.z, eb[6*HDIM+4*(m)+2], d6); d6 = fmaf(x##m.w, eb[6*HDIM+4*(m)+3], d6); \
    d7 = fmaf(x##m.x, eb[7*HDIM+4*(m)+0], d7); d7 = fmaf(x##m.y, eb[7*HDIM+4*(m)+1], d7); \
    d7 = fmaf(x##m.z, eb[7*HDIM+4*(m)+2], d7); d7 = fmaf(x##m.w, eb[7*HDIM+4*(m)+3], d7);
    for (int k0 = 0; k0 < KCODES; k0 += 8) {
        const float* eb = emb + (size_t)k0 * HDIM;
        float d0 = 0.f, d1 = 0.f, d2 = 0.f, d3 = 0.f;
        float d4 = 0.f, d5 = 0.f, d6 = 0.f, d7 = 0.f;
        R32(SC)
        float dd;
        dd = (vv - 2.f * d0) + ee_s[k0 + 0]; if (dd < best) { best = dd; bi = k0 + 0; }
        dd = (vv - 2.f * d1) + ee_s[k0 + 1]; if (dd < best) { best = dd; bi = k0 + 1; }
        dd = (vv - 2.f * d2) + ee_s[k0 + 2]; if (dd < best) { best = dd; bi = k0 + 2; }
        dd = (vv - 2.f * d3) + ee_s[k0 + 3]; if (dd < best) { best = dd; bi = k0 + 3; }
        dd = (vv - 2.f * d4) + ee_s[k0 + 4]; if (dd < best) { best = dd; bi = k0 + 4; }
        dd = (vv - 2.f * d5) + ee_s[k0 + 5]; if (dd < best) { best = dd; bi = k0 + 5; }
        dd = (vv - 2.f * d6) + ee_s[k0 + 6]; if (dd < best) { best = dd; bi = k0 + 6; }
        dd = (vv - 2.f * d7) + ee_s[k0 + 7]; if (dd < best) { best = dd; bi = k0 + 7; }
    }

    float lg[ADIM];
#pragma unroll
    for (int a = 0; a < ADIM; ++a) lg[a] = ba[a];
    float val = bv[0];
    const float4* q4 = (const float4*)(emb + (size_t)bi * HDIM);
#pragma unroll
    for (int j4 = 0; j4 < HDIM / 4; ++j4) {
        float4 q = q4[j4];
        const int j = 4 * j4;
#pragma unroll
        for (int a = 0; a < ADIM; ++a) {
            float t = lg[a];
            t = fmaf(q.x, Wa[(j + 0) * ADIM + a], t);
            t = fmaf(q.y, Wa[(j + 1) * ADIM + a], t);
            t = fmaf(q.z, Wa[(j + 2) * ADIM + a], t);
            t = fmaf(q.w, Wa[(j + 3) * ADIM + a], t);
            lg[a] = t;
        }
        val = fmaf(q.x, Wv[j + 0], val);
        val = fmaf(q.y, Wv[j + 1], val);
        val = fmaf(q.z, Wv[j + 2], val);
        val = fmaf(q.w, Wv[j + 3], val);
    }
    float m = lg[0];
#pragma unroll
    for (int a = 1; a < ADIM; ++a) m = fmaxf(m, lg[a]);
    float p[ADIM];
    float s = 0.f;
#pragma unroll
    for (int a = 0; a < ADIM; ++a) { p[a] = __expf(lg[a] - m); s += p[a]; }
    const float inv = 1.f / s;
    float4* outp = (float4*)(out + (size_t)row * ADIM);
    outp[0] = make_float4(p[0] * inv, p[1] * inv, p[2] * inv, p[3] * inv);
    outp[1] = make_float4(p[4] * inv, p[5] * inv, p[6] * inv, p[7] * inv);
    out[(size_t)NROWS * ADIM + row] = val;
}

// ===========================================================================
extern "C" void kernel_launch(void* const* d_in, const int* in_sizes, int n_in,
                              void* d_out, int out_size, void* d_ws, size_t ws_size,
                              hipStream_t stream) {
    const float* in  = (const float*)d_in[0];
    const float* W1  = (const float*)d_in[1];
    const float* b1  = (const float*)d_in[2];
    const float* Wh  = (const float*)d_in[3];
    const float* bh  = (const float*)d_in[4];
    const float* emb = (const float*)d_in[5];
    const float* Wa  = (const float*)d_in[6];
    const float* ba  = (const float*)d_in[7];
    const float* Wv  = (const float*)d_in[8];
    const float* bv  = (const float*)d_in[9];
    float* out = (float*)d_out;

    const size_t eT_bytes = (size_t)KCODES * HDIM * sizeof(float);   // 256 KB
    const size_t ee_bytes = KCODES * sizeof(float);                  // 2 KB
    const size_t need1 = (size_t)NROWS * HDIM * sizeof(float) + eT_bytes + ee_bytes;
    const size_t need2 = (size_t)(NROWS / 2) * HDIM * sizeof(float) + eT_bytes + ee_bytes;

    int nchunks, rstride;
    if (ws_size >= need1)      { nchunks = 1; rstride = NROWS; }
    else if (ws_size >= need2) { nchunks = 2; rstride = NROWS / 2; }
    else {
        fused_global_kernel<<<NROWS / 256, 256, 0, stream>>>(in, W1, b1, Wh, bh, emb,
                                                             Wa, ba, Wv, bv, out);
        return;
    }

    float* x2t = (float*)d_ws;
    float* eTp = x2t + (size_t)rstride * HDIM;
    float* eew = eTp + (size_t)KCODES * HDIM;

    prep_e_kernel<<<64, 256, 0, stream>>>(emb, eTp);
    ee_kernel<<<2, 256, 0, stream>>>(emb, eew);

    for (int c = 0; c < nchunks; ++c) {
        mlp_kernel<<<rstride / 128, 256, 0, stream>>>(in, W1, b1, Wh, bh,
                                                      x2t, c * rstride, rstride);
        score_kernel<<<rstride / 128, 256, 0, stream>>>(x2t, eTp, eew, emb,
                                                        Wa, ba, Wv, bv, out,
                                                        c * rstride, rstride);
    }
}